// Round 3
// baseline (95.441 us; speedup 1.0000x reference)
//
#include <hip/hip_runtime.h>
#include <math.h>

// FuzzyAND: out[b,j] = max(0, 1 - sum_i sigmoid(W)[i,j] * (1 - xs[b,i]))
// B=4096, IN=1024, OUT=1024, fp32 in/out.
//
// Certified-bound algorithm: with a_i = 1-xs[b,i] >= 0 and
// w_i = sigmoid(W[i,j]) in (0,1):
//     s[b,j] = sum_i a_i w_i  >=  (sum_i a_i) * min_i w_i = rowsum[b]*wmin[j]
// If rowsum[b]*wmin[j] > 1.01 (margin >> fp32 eval error; rowsum~512,
// wmin~0.03 -> bound~16 here) then s >= 1 exactly and out = 0 -- certified.
// Uncertified outputs (incl. NaN / xs>1, which poison rowsum to NaN and fail
// the > test) are computed EXACTLY inline in fp32. Correct for all inputs.
// sigmoid monotone -> min_i sigmoid(W[i,j]) = sigmoid(min_i W[i,j]):
// column mins on RAW weights, one sigmoid at the end.
//
// R13: SINGLE regular launch (one graph node). R10 vs R12 showed total time
// is insensitive to where kernel work lives (~31us side budget vs ~8us of
// roofline work) -> per-node graph overhead dominates. R11's cg grid.sync
// regressed (cooperative launch + full-barrier cost). Here: producer/consumer
// flag sync INSIDE one regular kernel.
//   blocks 0..127: write pmin[32][1024] partials, then per-block sentinel
//                  (release, agent scope -> L2 writeback).
//   all 512 blocks: local rowsums for their 8 rows (overlaps producers),
//                  spin on the 128 sentinels (relaxed agent loads), one
//                  acquire fence (invalidates stale per-XCD L2), fold,
//                  certify, write.
// Deadlock-safe by capacity: __launch_bounds__(256,2) => >=2 blocks/CU =>
// all 512 blocks co-resident; producers wait on nobody. Sentinel is an
// explicit value (not a counter), correct for ANY initial ws contents
// (harness poisons ws with 0xAA every replay; first iter may differ).
// ws: pmin[32][1024] f32 @0 (128 KB); flag[128] u32 @128 KB.

constexpr int Bsz = 4096;
constexpr int IN  = 1024;
constexpr int OUT = 1024;
constexpr int GRID = 512;
constexpr int RPB  = Bsz / GRID;        // 8 rows per block
constexpr unsigned SENT = 0x13371337u;  // != 0xAAAAAAAA poison, != 0

// exact fp32 dot for uncertified outputs (rare; never on bench distribution)
__device__ __noinline__ float exact_out(const float* xs, const float* w,
                                        int brow, int j) {
    float s = 0.0f;
#pragma unroll 4
    for (int i = 0; i < IN; ++i)
        s += (1.0f - xs[(size_t)brow * IN + i]) *
             (1.0f / (1.0f + expf(-w[(size_t)i * OUT + j])));
    float v = 1.0f - s;
    return v > 0.0f ? v : 0.0f;
}

__global__ __launch_bounds__(256, 2) void fuzzy_one(
        const float* __restrict__ xs, const float* __restrict__ w,
        float* __restrict__ pmin, unsigned* __restrict__ flag,
        float* __restrict__ out) {
    __shared__ float rs[RPB];
    const int g    = blockIdx.x;     // 0..511
    const int t    = threadIdx.x;    // 0..255
    const int wave = t >> 6;
    const int lane = t & 63;

    // ---- producers first: W column-min partials (blocks 0..127).
    // Block-uniform branch; done before rowsums so consumers wait least.
    if (g < 128) {
        const int ic = g >> 2;                  // [0,32) 32-row chunk of W
        const int jj = (g & 3) * 256 + t;       // column
        const float* base = w + (size_t)(ic * 32) * OUT + jj;
        float m = 1e30f;
#pragma unroll
        for (int r = 0; r < 32; ++r) m = fminf(m, base[(size_t)r * OUT]);
        pmin[ic * OUT + jj] = m;
        __syncthreads();   // drains vmcnt: all 256 partial stores are in L2
        if (t == 0)        // release at agent scope: L2 writeback, then sentinel
            __hip_atomic_store(&flag[g], SENT, __ATOMIC_RELEASE,
                               __HIP_MEMORY_SCOPE_AGENT);
    }

    // ---- all blocks: local rowsums of (1-xs) for this block's 8 rows.
    // Overlaps producer completion on other CUs.
#pragma unroll
    for (int rr = 0; rr < 2; ++rr) {
        const int b = g * RPB + wave * 2 + rr;
        const float4* p = (const float4*)(xs + (size_t)b * IN);
        float s = 0.0f, xmax = -1e30f;
#pragma unroll
        for (int r = 0; r < 4; ++r) {
            float4 v = p[r * 64 + lane];
            s += (1.0f - v.x) + (1.0f - v.y) + (1.0f - v.z) + (1.0f - v.w);
            xmax = fmaxf(xmax, fmaxf(fmaxf(v.x, v.y), fmaxf(v.z, v.w)));
        }
#pragma unroll
        for (int off = 32; off; off >>= 1) {
            s += __shfl_xor(s, off);
            xmax = fmaxf(xmax, __shfl_xor(xmax, off));
        }
        if (lane == 0) {
            // xs > 1 would make a_i < 0, invalidating the bound: poison to NaN
            // so every certificate on this row fails -> exact fallback path.
            rs[wave * 2 + rr] = (xmax <= 1.0f) ? s : (0.0f / 0.0f);
        }
    }

    // ---- wait for all 128 producer sentinels (threads 0..127 each poll one).
    if (t < 128) {
        while (__hip_atomic_load(&flag[t], __ATOMIC_RELAXED,
                                 __HIP_MEMORY_SCOPE_AGENT) != SENT)
            __builtin_amdgcn_s_sleep(2);
    }
    __syncthreads();                                   // also publishes rs[]
    __builtin_amdgcn_fence(__ATOMIC_ACQUIRE, "agent"); // invalidate stale L1/L2

    // ---- fold pmin partials, one sigmoid per column.
    const int j = t * 4;
    float4 m4 = make_float4(1e30f, 1e30f, 1e30f, 1e30f);
#pragma unroll
    for (int ic = 0; ic < 32; ++ic) {
        float4 p = *(const float4*)(pmin + ic * OUT + j);
        m4.x = fminf(m4.x, p.x); m4.y = fminf(m4.y, p.y);
        m4.z = fminf(m4.z, p.z); m4.w = fminf(m4.w, p.w);
    }
    float4 wm;
    wm.x = 1.0f / (1.0f + expf(-m4.x));
    wm.y = 1.0f / (1.0f + expf(-m4.y));
    wm.z = 1.0f / (1.0f + expf(-m4.z));
    wm.w = 1.0f / (1.0f + expf(-m4.w));

    // ---- certify + write this block's 8 rows.
#pragma unroll
    for (int b = 0; b < RPB; ++b) {
        const int brow = g * RPB + b;
        const float r = rs[b];
        float4 v = make_float4(0.0f, 0.0f, 0.0f, 0.0f);
        // certificate: r*wm > 1.01 (margin >> all fp32 eval error) => out = 0
        bool c0 = r * wm.x > 1.01f, c1 = r * wm.y > 1.01f;
        bool c2 = r * wm.z > 1.01f, c3 = r * wm.w > 1.01f;
        if (!(c0 && c1 && c2 && c3)) {   // wave-skipped via execz when all certify
            if (!c0) v.x = exact_out(xs, w, brow, j + 0);
            if (!c1) v.y = exact_out(xs, w, brow, j + 1);
            if (!c2) v.z = exact_out(xs, w, brow, j + 2);
            if (!c3) v.w = exact_out(xs, w, brow, j + 3);
        }
        *(float4*)(out + (size_t)brow * OUT + j) = v;
    }
}

extern "C" void kernel_launch(void* const* d_in, const int* in_sizes, int n_in,
                              void* d_out, int out_size, void* d_ws, size_t ws_size,
                              hipStream_t stream) {
    const float* xs = (const float*)d_in[0];   // [4096][1024]
    const float* wt = (const float*)d_in[1];   // [1024][1024]
    float* out  = (float*)d_out;               // [4096][1024]
    float* pmin = (float*)d_ws;                // 128 KB partial column mins
    unsigned* flag = (unsigned*)((char*)d_ws + 32 * OUT * sizeof(float));

    fuzzy_one<<<GRID, 256, 0, stream>>>(xs, wt, pmin, flag, out);
}

// Round 4
// 90.116 us; speedup vs baseline: 1.0591x; 1.0591x over previous
//
#include <hip/hip_runtime.h>
#include <math.h>

// FuzzyAND: out[b,j] = max(0, 1 - sum_i sigmoid(W)[i,j] * (1 - xs[b,i]))
// B=4096, IN=1024, OUT=1024, fp32 in/out.
//
// R14: ONE kernel, NO cross-block dependency, NO ws use.
// Measured so far: fill(ws poison, untouchable) = 44.5us; two-kernel
// structure = 76us regardless of work split (R10 vs R12); in-kernel
// device-scope sync costs ~+35us (R11 cg.sync 51.7us kernel, R13 flag-sync
// 95.4us total). So the only remaining lever is removing the cross-block
// wmin dependency altogether.
//
// Subset certificate: for ANY subset S of features, with a_i = 1-xs[b,i],
// all a_i >= 0 (checked on the FULL row) and w_i = sigmoid(W[i,j]) > 0:
//     s[b,j] >= (sum_{i in S} a_i) * min_{i in S} w_i
// If that bound > 1.01 (margin >> fp32 eval error) then out = 0 certified.
// Each block certifies with S1 = first 128 features: partial rowsums come
// from the full xs rows it already reads for validity; wmin over W rows
// [0,128) is computed BLOCK-LOCALLY (512 KB, same rows for every block ->
// L2/L3 resident; aggregate ~128 MB L2 ~ 3.7us). Columns with an unlucky
// very-negative early weight escalate per-wave:
//   tier2a: extend min to rows [0,256)  + rowsum[0,256)   (~59% of waves)
//   tier2b: extend min to full column   + full rowsum      (rare)
//   tier3 : exact fp32 dot per element                     (never on bench)
// Validity (a_i >= 0 for ALL i, incl. i not in S, and no NaN) via
// xmax <= 1 && sumF==sumF on the full row; invalid rows poison all three
// rowsums to NaN -> every certificate clause fails -> exact path. Correct
// for all inputs (same W-NaN exposure as accepted R10-R12: fminf skips NaN).
// ws: UNUSED (the 256 MiB poison fill remains, but no node depends on it).

constexpr int Bsz = 4096;
constexpr int IN  = 1024;
constexpr int OUT = 1024;
constexpr int GRID = 256;
constexpr int RPB  = Bsz / GRID;   // 16 rows per block
constexpr int S1 = 128;            // tier-1 subset (W rows [0,128))
constexpr int S2 = 256;            // tier-2a subset

__device__ __forceinline__ float4 min4(float4 a, float4 b) {
    return make_float4(fminf(a.x, b.x), fminf(a.y, b.y),
                       fminf(a.z, b.z), fminf(a.w, b.w));
}
__device__ __forceinline__ float4 sig4(float4 m) {
    return make_float4(1.0f / (1.0f + expf(-m.x)), 1.0f / (1.0f + expf(-m.y)),
                       1.0f / (1.0f + expf(-m.z)), 1.0f / (1.0f + expf(-m.w)));
}

// exact fp32 dot for uncertified outputs (rare; never on bench distribution)
__device__ __noinline__ float exact_out(const float* xs, const float* w,
                                        int brow, int j) {
    float s = 0.0f;
#pragma unroll 4
    for (int i = 0; i < IN; ++i)
        s += (1.0f - xs[(size_t)brow * IN + i]) *
             (1.0f / (1.0f + expf(-w[(size_t)i * OUT + j])));
    float v = 1.0f - s;
    return v > 0.0f ? v : 0.0f;
}

__global__ __launch_bounds__(256) void fuzzy_all(
        const float* __restrict__ xs, const float* __restrict__ w,
        float* __restrict__ out) {
    __shared__ float rs1[RPB], rs2[RPB], rsF[RPB];
    const int g    = blockIdx.x;     // 0..255
    const int t    = threadIdx.x;    // 0..255
    const int wave = t >> 6;         // 0..3
    const int lane = t & 63;

    // ---- phase 1: full xs rows (validity + 3-level rowsums), 4 rows/wave.
#pragma unroll
    for (int rr = 0; rr < 4; ++rr) {
        const int b = g * RPB + wave * 4 + rr;
        const float4* p = (const float4*)(xs + (size_t)b * IN);
        float s1 = 0.0f, s2 = 0.0f, sF = 0.0f, xmax = -1e30f;
#pragma unroll
        for (int r = 0; r < 4; ++r) {
            float4 v = p[r * 64 + lane];   // cols [(r*64+lane)*4 ..+4)
            float c = (1.0f - v.x) + (1.0f - v.y) + (1.0f - v.z) + (1.0f - v.w);
            sF += c;
            if (r == 0) {                  // cols [0,256)
                s2 += c;
                if (lane < 32) s1 += c;    // cols [0,128)
            }
            xmax = fmaxf(xmax, fmaxf(fmaxf(v.x, v.y), fmaxf(v.z, v.w)));
        }
#pragma unroll
        for (int off = 32; off; off >>= 1) {
            s1 += __shfl_xor(s1, off);
            s2 += __shfl_xor(s2, off);
            sF += __shfl_xor(sF, off);
            xmax = fmaxf(xmax, __shfl_xor(xmax, off));
        }
        if (lane == 0) {
            // Validity of the SUBSET bound needs a_i >= 0 for ALL i (dropped
            // terms must be nonneg) and no NaN anywhere: xmax<=1 (false for
            // NaN xmax) AND sF==sF (catches NaN beyond the xmax fmaxf-skip).
            const float nanv = 0.0f / 0.0f;
            const bool ok = (xmax <= 1.0f) && (sF == sF);
            rs1[wave * 4 + rr] = ok ? s1 : nanv;
            rs2[wave * 4 + rr] = ok ? s2 : nanv;
            rsF[wave * 4 + rr] = ok ? sF : nanv;
        }
    }

    // ---- phase 2: block-local column min over W rows [0,S1), 4 cols/thread.
    const int j = t * 4;
    float4 ma = make_float4(1e30f, 1e30f, 1e30f, 1e30f);
    float4 mb = ma;
#pragma unroll 8
    for (int r = 0; r < S1; r += 2) {   // two accumulators: break dep chain
        ma = min4(ma, *(const float4*)(w + (size_t)r * OUT + j));
        mb = min4(mb, *(const float4*)(w + (size_t)(r + 1) * OUT + j));
    }
    float4 m1 = min4(ma, mb);
    float4 wm1 = sig4(m1);

    __syncthreads();   // rs*[] ready

    // block-wide min rowsums (fminf skips NaN rows: those rows simply fail
    // their per-row certs in phase 3 and go exact -- intended).
    float rmin1 = 1e30f, rmin2 = 1e30f, rminF = 1e30f;
#pragma unroll
    for (int b = 0; b < RPB; ++b) {
        rmin1 = fminf(rmin1, rs1[b]);
        rmin2 = fminf(rmin2, rs2[b]);
        rminF = fminf(rminF, rsF[b]);
    }

    // ---- tiered escalation (wave-uniform, coalesced like phase 2).
    float4 wm2 = make_float4(0.0f, 0.0f, 0.0f, 0.0f);   // 0 => clause false
    float4 wmF = wm2;
    const bool f1 = !(rmin1 * wm1.x > 1.01f) || !(rmin1 * wm1.y > 1.01f) ||
                    !(rmin1 * wm1.z > 1.01f) || !(rmin1 * wm1.w > 1.01f);
    if (__any(f1)) {
        float4 m2 = m1;
#pragma unroll 8
        for (int r = S1; r < S2; ++r)
            m2 = min4(m2, *(const float4*)(w + (size_t)r * OUT + j));
        wm2 = sig4(m2);
        const bool f2 = !(rmin2 * wm2.x > 1.01f) || !(rmin2 * wm2.y > 1.01f) ||
                        !(rmin2 * wm2.z > 1.01f) || !(rmin2 * wm2.w > 1.01f);
        if (__any(f2)) {
            float4 mF = m2;
#pragma unroll 4
            for (int r = S2; r < IN; ++r)
                mF = min4(mF, *(const float4*)(w + (size_t)r * OUT + j));
            wmF = sig4(mF);
        }
    }

    // ---- phase 3: per-row certify (3 clauses), write 16 rows x float4.
#pragma unroll 4
    for (int b = 0; b < RPB; ++b) {
        const int brow = g * RPB + b;
        const float a1 = rs1[b], a2 = rs2[b], aF = rsF[b];
        float4 v = make_float4(0.0f, 0.0f, 0.0f, 0.0f);
        // NaN rowsums fail every clause -> exact. wm2/wmF are 0 unless their
        // tier ran, making those clauses false (0 > 1.01 == false).
        bool c0 = (a1 * wm1.x > 1.01f) || (a2 * wm2.x > 1.01f) || (aF * wmF.x > 1.01f);
        bool c1 = (a1 * wm1.y > 1.01f) || (a2 * wm2.y > 1.01f) || (aF * wmF.y > 1.01f);
        bool c2 = (a1 * wm1.z > 1.01f) || (a2 * wm2.z > 1.01f) || (aF * wmF.z > 1.01f);
        bool c3 = (a1 * wm1.w > 1.01f) || (a2 * wm2.w > 1.01f) || (aF * wmF.w > 1.01f);
        if (!(c0 && c1 && c2 && c3)) {   // wave-skipped via execz when all certify
            if (!c0) v.x = exact_out(xs, w, brow, j + 0);
            if (!c1) v.y = exact_out(xs, w, brow, j + 1);
            if (!c2) v.z = exact_out(xs, w, brow, j + 2);
            if (!c3) v.w = exact_out(xs, w, brow, j + 3);
        }
        *(float4*)(out + (size_t)brow * OUT + j) = v;
    }
}

extern "C" void kernel_launch(void* const* d_in, const int* in_sizes, int n_in,
                              void* d_out, int out_size, void* d_ws, size_t ws_size,
                              hipStream_t stream) {
    (void)d_ws; (void)ws_size;                 // workspace unused (R14)
    const float* xs = (const float*)d_in[0];   // [4096][1024]
    const float* wt = (const float*)d_in[1];   // [1024][1024]
    float* out = (float*)d_out;                // [4096][1024]

    fuzzy_all<<<GRID, 256, 0, stream>>>(xs, wt, out);
}

// Round 5
// 76.374 us; speedup vs baseline: 1.2497x; 1.1799x over previous
//
#include <hip/hip_runtime.h>
#include <math.h>

// FuzzyAND: out[b,j] = max(0, 1 - sum_i sigmoid(W)[i,j] * (1 - xs[b,i]))
// B=4096, IN=1024, OUT=1024, fp32 in/out.
//
// Certified-bound algorithm: with a_i = 1-xs[b,i] >= 0 and
// w_i = sigmoid(W[i,j]) in (0,1):
//     s[b,j] = sum_i a_i w_i  >=  (sum_i a_i) * min_i w_i = rowsum[b]*wmin[j]
// If rowsum[b]*wmin[j] > 1.01 (margin >> fp32 eval error; rowsum~512,
// wmin~0.03 -> bound~16 here) then s >= 1 exactly and out = 0 -- certified.
// Uncertified outputs (incl. NaN / xs>1, which poison rowsum to NaN and fail
// the > test) are computed EXACTLY inline in fp32. Correct for all inputs.
// sigmoid monotone -> min_i sigmoid(W[i,j]) = sigmoid(min_i W[i,j]):
// column mins on RAW weights, one sigmoid at the end.
//
// R15: REVERT to R12 (best measured). Structure->time map across the session:
//   two plain kernels (R10 split / R12 split) : 75.6 / 76.4 us  <- floor
//   one cooperative kernel + grid.sync (R11)  : 131 us
//   one kernel + release/acquire flags (R13)  : 95 us
//   one kernel, redundant local wmin (R14)    : 90 us
// Lessons (measured): node count is not the cost; work placement is not the
// cost; in-kernel device-scope sync costs ~+35us (8 non-coherent XCD L2s);
// redundant per-block W scans at 1 blk/CU cost +14us. The ~76us total =
// 44.5us harness ws-poison fill (untouchable) + ~15us kernels (mandatory
// ~36MB traffic, near HBM roofline) + ~16us fixed graph/dispatch overhead.
//   k1: 128 blocks, W column-min partials only (4 MB read).
//   k2: 512 blocks x 256 thr, 8 rows each: local rowsums (xs read once,
//       16 MB), fold 32 pmin partials (L2-hot), sigmoid, certify, write.
// ws: pmin[32][1024] f32 @0 (128 KB). All ws bytes read by k2 are written by
// k1 first (harness poisons ws with 0xAA every replay).

constexpr int Bsz = 4096;
constexpr int IN  = 1024;
constexpr int OUT = 1024;
constexpr int K2_GRID = 512;
constexpr int ROWS_PER_BLK = Bsz / K2_GRID;   // 8

// ---- k1: 128 blocks x 256 thr: column-min partials of W over 32-row chunks.
__global__ __launch_bounds__(256) void k1_wmin(const float* __restrict__ w,
                                               float* __restrict__ pmin) {
    const int ic = blockIdx.x >> 2;                 // [0,32) 32-row chunk
    const int j  = (blockIdx.x & 3) * 256 + threadIdx.x;
    const float* base = w + (size_t)(ic * 32) * OUT + j;
    float m = 1e30f;
#pragma unroll
    for (int r = 0; r < 32; ++r) m = fminf(m, base[(size_t)r * OUT]);
    pmin[ic * OUT + j] = m;
}

// exact fp32 dot for uncertified outputs (rare; never on bench distribution)
__device__ __noinline__ float exact_out(const float* xs, const float* w,
                                        int brow, int j) {
    float s = 0.0f;
#pragma unroll 4
    for (int i = 0; i < IN; ++i)
        s += (1.0f - xs[(size_t)brow * IN + i]) *
             (1.0f / (1.0f + expf(-w[(size_t)i * OUT + j])));
    float v = 1.0f - s;
    return v > 0.0f ? v : 0.0f;
}

// ---- k2: 512 blocks x 256 thr; block = 8 b-rows x all 1024 j.
// Phase A: 4 waves compute rowsums of (1-xs) for the block's 8 rows (2/wave).
// Phase B: thread t owns columns j=4t..4t+3: folds 32 pmin partials
// (float4, coalesced, L2-hot), one sigmoid per column, then 8 certified
// float4 stores.
__global__ __launch_bounds__(256) void k2_write(const float* __restrict__ xs,
                                                const float* __restrict__ w,
                                                const float* __restrict__ pmin,
                                                float* __restrict__ out) {
    __shared__ float rs[ROWS_PER_BLK];
    const int g    = blockIdx.x;
    const int t    = threadIdx.x;
    const int wave = t >> 6;
    const int lane = t & 63;

    // ---- phase A: local rowsums (no ws round-trip, no extra dispatch)
#pragma unroll
    for (int rr = 0; rr < 2; ++rr) {
        const int b = g * ROWS_PER_BLK + wave * 2 + rr;
        const float4* p = (const float4*)(xs + (size_t)b * IN);
        float s = 0.0f, xmax = -1e30f;
#pragma unroll
        for (int r = 0; r < 4; ++r) {
            float4 v = p[r * 64 + lane];
            s += (1.0f - v.x) + (1.0f - v.y) + (1.0f - v.z) + (1.0f - v.w);
            xmax = fmaxf(xmax, fmaxf(fmaxf(v.x, v.y), fmaxf(v.z, v.w)));
        }
#pragma unroll
        for (int off = 32; off; off >>= 1) {
            s += __shfl_xor(s, off);
            xmax = fmaxf(xmax, __shfl_xor(xmax, off));
        }
        if (lane == 0) {
            // xs > 1 would make a_i < 0, invalidating the bound: poison to NaN
            // so every certificate on this row fails -> exact fallback path.
            rs[wave * 2 + rr] = (xmax <= 1.0f) ? s : (0.0f / 0.0f);
        }
    }

    // ---- phase B: fold pmin partials, sigmoid once per column
    const int j = t * 4;
    float4 m4 = make_float4(1e30f, 1e30f, 1e30f, 1e30f);
#pragma unroll
    for (int ic = 0; ic < 32; ++ic) {
        float4 p = *(const float4*)(pmin + ic * OUT + j);
        m4.x = fminf(m4.x, p.x); m4.y = fminf(m4.y, p.y);
        m4.z = fminf(m4.z, p.z); m4.w = fminf(m4.w, p.w);
    }
    float4 wm;
    wm.x = 1.0f / (1.0f + expf(-m4.x));
    wm.y = 1.0f / (1.0f + expf(-m4.y));
    wm.z = 1.0f / (1.0f + expf(-m4.z));
    wm.w = 1.0f / (1.0f + expf(-m4.w));

    __syncthreads();   // rs[] ready

#pragma unroll
    for (int b = 0; b < ROWS_PER_BLK; ++b) {
        const int brow = g * ROWS_PER_BLK + b;
        const float r = rs[b];
        float4 v = make_float4(0.0f, 0.0f, 0.0f, 0.0f);
        // certificate: r*wm > 1.01 (margin >> all fp32 eval error) => out = 0
        bool c0 = r * wm.x > 1.01f, c1 = r * wm.y > 1.01f;
        bool c2 = r * wm.z > 1.01f, c3 = r * wm.w > 1.01f;
        if (!(c0 && c1 && c2 && c3)) {   // wave-skipped via execz when all certify
            if (!c0) v.x = exact_out(xs, w, brow, j + 0);
            if (!c1) v.y = exact_out(xs, w, brow, j + 1);
            if (!c2) v.z = exact_out(xs, w, brow, j + 2);
            if (!c3) v.w = exact_out(xs, w, brow, j + 3);
        }
        *(float4*)(out + (size_t)brow * OUT + j) = v;
    }
}

extern "C" void kernel_launch(void* const* d_in, const int* in_sizes, int n_in,
                              void* d_out, int out_size, void* d_ws, size_t ws_size,
                              hipStream_t stream) {
    const float* xs = (const float*)d_in[0];   // [4096][1024]
    const float* wt = (const float*)d_in[1];   // [1024][1024]
    float* out  = (float*)d_out;               // [4096][1024]
    float* pmin = (float*)d_ws;                // 128 KB partial column mins

    k1_wmin<<<128, 256, 0, stream>>>(wt, pmin);
    k2_write<<<K2_GRID, 256, 0, stream>>>(xs, wt, pmin, out);
}